// Round 6
// baseline (407.420 us; speedup 1.0000x reference)
//
#include <hip/hip_runtime.h>
#include <stdint.h>
#include <math.h>

typedef unsigned int u32;
typedef unsigned long long u64;

#define E_CNT   8192
#define N_CNT   4096
#define OUT_K   16384          // K*E = 2*8192
#define NODE_BM_WORDS 128      // 4096 bits / 32
#define NB      512            // persistent grid: 512 blocks x 1024 thr (=2/CU, co-resident)
#define NT      1024
#define ELEMS_PER_BLOCK 131072u // 2^26 / 512  (= chunks 2b, 2b+1)

// ---- workspace layout (bytes) ----
#define OFF_BAD      0x000000  // u32[4096*128]  2 MiB
#define OFF_CNT_DST  0x200000  // u32[4096]
#define OFF_CNT_SRC  0x204000  // u32[4096]
#define OFF_CCOUNT   0x208000  // u32[1024] chunk counts (single-writer, no zero needed)
#define OFF_SCALARS  0x209000  // [0]=num_neg [1]=ticket [2]=T9 [3..6]=bar0..3
#define OFF_KEEPBM   0x210000  // u64[1<<20]  8 MiB
#define ZERO_WORDS   (0x208000 / 4)   // zero bad+cnt_dst+cnt_src inside kernel

// rotl as a single v_alignbit_b32
__device__ __forceinline__ u32 rotl32(u32 x, u32 d) {
  return __builtin_amdgcn_alignbit(x, x, 32u - d);
}

// Two interleaved JAX threefry2x32 evals, key=(0,42), counters (0,ia),(0,ib).
// Returns bits = o0 ^ o1 (partitionable 32-bit draw). Verified absmax=0 (R2-R5).
__device__ __forceinline__ void threefry2_0_42(u32 ia, u32 ib, u32& bits_a, u32& bits_b) {
  const u32 k1 = 42u, k2 = 0x1BD11BF0u; // 0 ^ 42 ^ 0x1BD11BDA
  u32 A0 = 0u, A1 = ia + k1;
  u32 B0 = 0u, B1 = ib + k1;
#define R2(r) { A0 += A1; B0 += B1; A1 = rotl32(A1, r); B1 = rotl32(B1, r); A1 ^= A0; B1 ^= B0; }
  R2(13) R2(15) R2(26) R2(6)
  A0 += k1; B0 += k1; A1 += k2 + 1u; B1 += k2 + 1u;
  R2(17) R2(29) R2(16) R2(24)
  A0 += k2; B0 += k2; A1 += 2u; B1 += 2u;
  R2(13) R2(15) R2(26) R2(6)
  A1 += k1 + 3u; B1 += k1 + 3u;
  R2(17) R2(29) R2(16) R2(24)
  A0 += k1; B0 += k1; A1 += k2 + 4u; B1 += k2 + 4u;
  R2(13) R2(15) R2(26) R2(6)
  A0 += k2; B0 += k2; A1 += 5u; B1 += 5u;
#undef R2
  bits_a = A0 ^ A1;
  bits_b = B0 ^ B1;
}

// device-scope grid barrier (counters pre-zeroed by host memset)
__device__ __forceinline__ void gbar(u32* bar) {
  __syncthreads();
  if (threadIdx.x == 0) {
    __threadfence();                          // release my block's writes
    atomicAdd(bar, 1u);
    while (atomicAdd(bar, 0u) < (u32)NB) __builtin_amdgcn_s_sleep(2);
    __threadfence();                          // acquire others' writes
  }
  __syncthreads();
}

// 1024-thread inclusive scan (Hillis-Steele in LDS)
__device__ __forceinline__ u32 block_scan(u32 v, u32* s) {
  int t = threadIdx.x;
  s[t] = v; __syncthreads();
  for (int off = 1; off < NT; off <<= 1) {
    u32 x = (t >= off) ? s[t - off] : 0u;
    __syncthreads();
    s[t] += x;
    __syncthreads();
  }
  u32 r = s[t];
  __syncthreads();   // s[] safe to reuse after return
  return r;
}

__global__ void __launch_bounds__(NT, 8) k_all(const int* __restrict__ src,
                                               const int* __restrict__ dst,
                                               u32* __restrict__ ws32,
                                               u64* __restrict__ keep_bm,
                                               int* __restrict__ out) {
  u32* bad     = ws32 + (OFF_BAD >> 2);
  u32* cnt_dst = ws32 + (OFF_CNT_DST >> 2);
  u32* cnt_src = ws32 + (OFF_CNT_SRC >> 2);
  u32* ccount  = ws32 + (OFF_CCOUNT >> 2);
  u32* scal    = ws32 + (OFF_SCALARS >> 2);
  u32* bars    = scal + 3;

  const u32 b = blockIdx.x, t = threadIdx.x;
  const u32 wv = t >> 6, ln = t & 63;
  const u32 g = b * NT + t;                  // < 524288

  __shared__ u32 s[NT];
  __shared__ u32 part[16];
  __shared__ u32 wsum[16];
  __shared__ u32 sh_t9;
  __shared__ u32 chunk_off[2];

  // ---- phase 0: zero bad + histograms ----
  ws32[g] = 0;
  if (g < (u32)(ZERO_WORDS - NB * NT)) ws32[NB * NT + g] = 0;   // 8192 tail words
  gbar(&bars[0]);

  // ---- phase 1: build bad bitmap + histograms + output prefill ----
  if (g < N_CNT) atomicOr(&bad[g * NODE_BM_WORDS + (g >> 5)], 1u << (g & 31));
  if (g < E_CNT) {
    u32 sv = (u32)src[g], dv = (u32)dst[g];
    atomicOr(&bad[sv * NODE_BM_WORDS + (dv >> 5)], 1u << (dv & 31));
    atomicAdd(&cnt_dst[dv], 1u);
    atomicAdd(&cnt_src[sv], 1u);
    int s0 = src[0], d0 = dst[0];            // nonzero fill_value=0 -> (src[0], dst[0])
    out[g] = s0;           out[g + E_CNT] = s0;
    out[OUT_K + g] = d0;   out[OUT_K + g + E_CNT] = d0;
  }
  gbar(&bars[1]);

  // ---- phase 2: num_negatives + T9 threshold ----
  if (t < 16) part[t] = 0;
  __syncthreads();
  u32 gw = b * 16 + wv;                      // one node row per wave, rows < 4096
  if (gw < N_CNT) {
    const u32* row = bad + gw * NODE_BM_WORDS;
    u32 sum = 0;
#pragma unroll
    for (int h = 0; h < 2; ++h) {
      u32 w = ln + h * 64u;
      u32 bits = row[w];
      while (bits) { int bb = __ffs(bits) - 1; sum += cnt_dst[(w << 5) + bb]; bits &= bits - 1; }
    }
#pragma unroll
    for (int off = 32; off > 0; off >>= 1) sum += __shfl_down(sum, off, 64);
    if (ln == 0) part[wv] = ((u32)E_CNT - sum) * cnt_src[gw];
  }
  __syncthreads();
  if (t == 0) {
    u32 tot = 0;
#pragma unroll
    for (int k = 0; k < 16; ++k) tot += part[k];
    if (tot) atomicAdd(&scal[0], tot);
    __threadfence();
    if (atomicAdd(&scal[1], 1u) == (u32)(NB - 1)) {   // last block: compute threshold
      u32 nn = atomicAdd(&scal[0], 0u);
      u32 ratio = nn >> 13;                  // num_neg // E
      float kp = 2.0f / (float)ratio;        // f32(K)/f32(ratio), as JAX
      // u = m*2^-23 exact; u < kp <=> m < T = ceil(kp*2^23) <=> bits < T<<9
      u32 T = (u32)ceil((double)kp * 8388608.0);
      u32 T9 = (T >= (1u << 23)) ? 0xFFFFFFFFu : (T << 9);
      atomicExch(&scal[2], T9);
    }
  }
  gbar(&bars[2]);
  if (t == 0) sh_t9 = atomicAdd(&scal[2], 0u);
  __syncthreads();
  const u32 T9 = sh_t9;

  // ---- phase 3: sample (block b owns elements [b*131072, +131072) = chunks 2b,2b+1) ----
  const u32 eb = b * ELEMS_PER_BLOCK + wv * 8192u;   // wave's 8192-elem span (one chunk)
  u32 wave_c = 0;
  for (int it = 0; it < 16; ++it) {
    u32 i0w = eb + (u32)it * 512u;
    u64 words[8];
    u64 any = 0;
#pragma unroll
    for (int j = 0; j < 4; ++j) {
      u32 ia = i0w + (u32)j * 128u + ln;
      u32 ba, bb;
      threefry2_0_42(ia, ia + 64u, ba, bb);
      u64 ma = __ballot(ba < T9);
      u64 mb = __ballot(bb < T9);
      words[2 * j] = ma; words[2 * j + 1] = mb;
      any |= ma | mb;
    }
    if (any) {   // rare: refine kept lanes against bad bitmap
#pragma unroll
      for (int k = 0; k < 8; ++k) {
        if (words[k]) {
          u32 i = i0w + (u32)k * 64u + ln;
          bool kp = (words[k] >> ln) & 1ull;
          if (kp) {
            u32 n = (u32)src[i >> 13]; u32 v = (u32)dst[i & 8191];
            kp = ((bad[n * NODE_BM_WORDS + (v >> 5)] >> (v & 31)) & 1u) == 0u;
          }
          words[k] = __ballot(kp);
        }
      }
    }
    if (ln == 0) {
      ulonglong2* p = (ulonglong2*)&keep_bm[i0w >> 6];   // 64B-aligned
      p[0] = make_ulonglong2(words[0], words[1]);
      p[1] = make_ulonglong2(words[2], words[3]);
      p[2] = make_ulonglong2(words[4], words[5]);
      p[3] = make_ulonglong2(words[6], words[7]);
      u32 c = 0;
#pragma unroll
      for (int k = 0; k < 8; ++k) c += (u32)__popcll(words[k]);
      wave_c += c;
    }
  }
  if (ln == 0) wsum[wv] = wave_c;
  __syncthreads();
  if (t < 2) {   // chunk totals: single writer, plain store (no zeroing needed)
    u32 cs = 0;
#pragma unroll
    for (int k = 0; k < 8; ++k) cs += wsum[t * 8 + k];
    ccount[b * 2 + t] = cs;
  }
  gbar(&bars[3]);

  // ---- phase 4: ordered compaction of chunks 2b, 2b+1 (own keep_bm, no cross-block) ----
  u32 cval = ccount[t];                       // all 1024 chunk counts
  u32 incl = block_scan(cval, s);
  if (t == 2 * b)     chunk_off[0] = incl - cval;
  if (t == 2 * b + 1) chunk_off[1] = incl - cval;
  __syncthreads();
#pragma unroll
  for (int k = 0; k < 2; ++k) {
    u32 c = 2 * b + (u32)k;
    u64 w = keep_bm[c * 1024u + t];           // 1 word/thread
    u32 pc = (u32)__popcll(w);
    u32 incl2 = block_scan(pc, s);
    u32 rank = chunk_off[k] + incl2 - pc;
    u32 tt0 = (c << 16) + (t << 6);
    while (w) {
      int bb = __ffsll((unsigned long long)w) - 1;
      if (rank < OUT_K) {
        u32 tt = tt0 + (u32)bb;
        out[rank]         = src[tt >> 13];    // edge_src[rows]
        out[OUT_K + rank] = dst[tt & 8191];   // edge_dst[cols]
      }
      rank++;
      w &= w - 1;
    }
  }
}

extern "C" void kernel_launch(void* const* d_in, const int* in_sizes, int n_in,
                              void* d_out, int out_size, void* d_ws, size_t ws_size,
                              hipStream_t stream) {
  const int* src = (const int*)d_in[1];  // edge_src
  const int* dst = (const int*)d_in[2];  // edge_dst  (node_feature d_in[0] unused)
  int* out = (int*)d_out;                // [edge_src_neg(16384) | edge_dst_neg(16384)]
  char* ws = (char*)d_ws;

  // zero only the scalar/barrier block (64 B); everything else is kernel-initialized
  hipMemsetAsync(ws + OFF_SCALARS, 0, 64, stream);
  k_all<<<NB, NT, 0, stream>>>(src, dst, (u32*)ws, (u64*)(ws + OFF_KEEPBM), out);
}